// Round 7
// baseline (163.656 us; speedup 1.0000x reference)
//
#include <hip/hip_runtime.h>

#define NN 50000
#define NE 600000
#define NR 500
#define DD 128
#define NSUB 8    // one sub-bucket per XCD
#define CAP8 16   // per-sub capacity; deg/8 ~ Poisson(1.5), P(>16) ~ 1e-13

// NOTE (r3): hipLaunchCooperativeKernel is NOT capturable by this harness's
// hipGraph (silent launch failure -> all-zero output). Multi-dispatch only.
// NOTE (r4): __builtin_nontemporal_load needs ext_vector pointers, not float4.
// NOTE (r6): __device__ BSS survives (only d_ws is poisoned); fused restores
// the zero-cursor invariant after reading.
// NOTE (r7): 600k returning atomics to fabric-shared cursor lines ~= 7 line
// migrations/cycle device-wide (the ~40us fill floor). Per-XCD sub-buckets
// (blockIdx&7 ~ XCD, round-robin dispatch heuristic) keep cursor+slot lines
// owned by ONE XCD's L2 -> local atomics, no migrations. Mapping being wrong
// costs only speed, never correctness.
__device__ int g_cur8[NSUB][NN];   // 1.6 MB BSS, zero-init

// Zero rows: gather batches padded to 8 with a sentinel word pointing at an
// all-zero h_bf row (index NN) / rel_bf row (index NR) -> +0.0, L1-hot.
#define ZW ((unsigned)NN | ((unsigned)NR << 16))

// ---------------------------------------------------------------------------
// Workspace layout (int units):
//   OFF_BKT : NSUB*NN*CAP8 packed (src | typ<<16) sub-bucket slots (25.6 MB)
//   OFF_HB  : h as bf16   ((NN+1)*DD, last row = zeros)
//   OFF_RELB: rel as bf16 ((NR+1)*DD, last row = zeros)
//   OFF_BP  : [W;L] bf16 MFMA B-fragments (32768 bf16)
// ---------------------------------------------------------------------------
#define OFF_BKT  0
#define OFF_HB   (OFF_BKT + NSUB * NN * CAP8)
#define OFF_RELB (OFF_HB + (NN + 1) * DD / 2)
#define OFF_BP   (OFF_RELB + (NR + 1) * DD / 2)

typedef __bf16 bf16x8 __attribute__((ext_vector_type(8)));
typedef float  f32x4  __attribute__((ext_vector_type(4)));
typedef float  f32x4v __attribute__((ext_vector_type(4)));

#define FILL_BLOCKS ((NE + 255) / 256)   // 2344
#define HB_BLOCKS   3125   // 50000*128/8/256
#define RELB_BLOCKS 32     // 8000 conv threads + 32 zero-row threads
#define PB_BLOCKS   128    // 32768 threads
#define PREP_BLOCKS (FILL_BLOCKS + HB_BLOCKS + RELB_BLOCKS + PB_BLOCKS)

// ---------------------------------------------------------------------------
// prep_fill: (fill) XCD-local sub-bucket scatter, 1 edge/thread;
//            (a) h->bf16, (b) rel->bf16 (+ zero rows), (c) pack [W;L] into
//            MFMA B frags: n = ntile*16+(lane&15), k = kstep*32+(lane>>4)*8+j
// ---------------------------------------------------------------------------
__global__ __launch_bounds__(256) void prep_fill(
    const float* __restrict__ h, const float* __restrict__ rel,
    const float* __restrict__ W, const float* __restrict__ L,
    __bf16* __restrict__ h_bf, __bf16* __restrict__ rel_bf,
    __bf16* __restrict__ Bp,
    const int* __restrict__ esrc, const int* __restrict__ edst,
    const int* __restrict__ etyp, unsigned* __restrict__ bucket)
{
    int b = blockIdx.x;
    if (b < FILL_BLOCKS) {
        int e = b * 256 + threadIdx.x;
        if (e >= NE) return;
        int x = b & 7;               // ~XCD id (round-robin dispatch heuristic)
        int s = __builtin_nontemporal_load(esrc + e);
        int d = __builtin_nontemporal_load(edst + e);
        int t = __builtin_nontemporal_load(etyp + e);
        int pos = atomicAdd(&g_cur8[x][d], 1);   // XCD-local L2 atomic
        if (pos < CAP8)
            bucket[((size_t)x * NN + d) * CAP8 + pos] = (unsigned)s | ((unsigned)t << 16);
        return;
    }
    b -= FILL_BLOCKS;
    if (b < HB_BLOCKS) {
        int t = b * 256 + threadIdx.x;            // 8 floats per thread
        const f32x4v* src = (const f32x4v*)h + (size_t)t * 2;
        f32x4v v0 = __builtin_nontemporal_load(src);
        f32x4v v1 = __builtin_nontemporal_load(src + 1);
        bf16x8 o;
        o[0]=(__bf16)v0[0]; o[1]=(__bf16)v0[1]; o[2]=(__bf16)v0[2]; o[3]=(__bf16)v0[3];
        o[4]=(__bf16)v1[0]; o[5]=(__bf16)v1[1]; o[6]=(__bf16)v1[2]; o[7]=(__bf16)v1[3];
        *(bf16x8*)(h_bf + (size_t)t * 8) = o;
    } else if (b < HB_BLOCKS + RELB_BLOCKS) {
        int t = (b - HB_BLOCKS) * 256 + threadIdx.x;
        if (t < NR * DD / 8) {
            const f32x4v* src = (const f32x4v*)rel + (size_t)t * 2;
            f32x4v v0 = src[0], v1 = src[1];
            bf16x8 o;
            o[0]=(__bf16)v0[0]; o[1]=(__bf16)v0[1]; o[2]=(__bf16)v0[2]; o[3]=(__bf16)v0[3];
            o[4]=(__bf16)v1[0]; o[5]=(__bf16)v1[1]; o[6]=(__bf16)v1[2]; o[7]=(__bf16)v1[3];
            *(bf16x8*)(rel_bf + (size_t)t * 8) = o;
        } else if (t < NR * DD / 8 + 16) {         // h_bf zero row (index NN)
            int j = t - NR * DD / 8;
            bf16x8 z;
#pragma unroll
            for (int k = 0; k < 8; ++k) z[k] = (__bf16)0.f;
            *(bf16x8*)(h_bf + (size_t)NN * DD + j * 8) = z;
        } else if (t < NR * DD / 8 + 32) {         // rel_bf zero row (index NR)
            int j = t - NR * DD / 8 - 16;
            bf16x8 z;
#pragma unroll
            for (int k = 0; k < 8; ++k) z[k] = (__bf16)0.f;
            *(bf16x8*)(rel_bf + (size_t)NR * DD + j * 8) = z;
        }
    } else {
        int t = (b - HB_BLOCKS - RELB_BLOCKS) * 256 + threadIdx.x;  // [0,32768)
        int lane  = (t >> 3) & 63;
        int ntile = (t >> 9) & 7;
        int kstep = t >> 12;
        int n = ntile * 16 + (lane & 15);
        int k = kstep * 32 + (lane >> 4) * 8 + (t & 7);
        float v = (k < DD) ? W[k * DD + n] : L[(k - DD) * DD + n];
        Bp[t] = (__bf16)v;
    }
}

// ---------------------------------------------------------------------------
// fused_gather_mfma: 16 nodes per block (grid = NN/16 = 3125, exact).
//   phase 1: gather over the node's 8 sub-buckets as ONE virtual list
//     - 8 counts loaded FIRST (only dependency for word addresses), reset
//       after read (restores invariant; coalesced 64B runs per sub)
//     - virtual v -> (sub x, slot) via unrolled compare/select over the
//       register prefix p[] (all indexing compile-time -> no scratch)
//     - uniform masked 8-batches, invalid slots -> zero rows; next batch's
//       words prefetched (OOB offsets land inside ws; values discarded)
//   phase 2: all 4 waves share the 16 A-rows; wave w computes n-tiles
//            {2w, 2w+1}: 8 ksteps x 2 = 16 MFMA/wave. relu, nontemporal store.
// ---------------------------------------------------------------------------
#define AP 264   // bf16 pitch; row = 528 B (16B-aligned for b128)

__global__ __launch_bounds__(256) void fused_gather_mfma(
    const __bf16* __restrict__ h_bf, const __bf16* __restrict__ rel_bf,
    const float* __restrict__ norm,
    const unsigned* __restrict__ bucket, const __bf16* __restrict__ Bp,
    float* __restrict__ out)
{
    __shared__ __bf16 As[16 * AP];   // 8448 B
    int tid = threadIdx.x;
    int row0 = blockIdx.x * 16;
    int g    = tid >> 4;             // node group 0..15
    int gl   = tid & 15;             // lane within node: bf16 [gl*8, gl*8+8)
    int node = row0 + g;             // always < NN (exact grid)
    int nodeoff = node * CAP8;

    // counts first: the only dependency of the word addresses
    int c[8];
#pragma unroll
    for (int x = 0; x < 8; ++x) c[x] = g_cur8[x][node];
    if (gl < 8) g_cur8[gl][node] = 0;    // restore invariant (same-wave: loads
                                         // above issue before this store)
    bf16x8 own_h = *(const bf16x8*)(h_bf + (size_t)node * DD + gl * 8);
    float sc = norm[node];

    int p[9];
    p[0] = 0;
#pragma unroll
    for (int x = 0; x < 8; ++x) {
        int cc = c[x] < CAP8 ? c[x] : CAP8;
        p[x + 1] = p[x] + cc;
    }
    int n = p[8];                    // total degree (<=128)

    // virtual index -> word offset (compile-time p[] indexing only)
    auto voff = [&](int v) -> int {
        int x = 0, base = 0;
#pragma unroll
        for (int k = 1; k < 8; ++k) {
            if (v >= p[k]) { x = k; base = p[k]; }
        }
        return x * (NN * CAP8) + nodeoff + (v - base);
    };

    float acc[8];
#pragma unroll
    for (int j = 0; j < 8; ++j) acc[j] = 0.f;

    unsigned w[8];
#pragma unroll
    for (int u = 0; u < 8; ++u) w[u] = bucket[voff(u)];

    int nb = (n + 7) >> 3;
    for (int b = 0; b < nb; ++b) {
        int vbase = b * 8;
        bf16x8 a[8], r[8];
#pragma unroll
        for (int u = 0; u < 8; ++u) {
            unsigned wu = (vbase + u < n) ? w[u] : ZW;   // pad -> zero rows
            a[u] = *(const bf16x8*)(h_bf   + (size_t)(wu & 0xFFFFu) * DD + gl * 8);
            r[u] = *(const bf16x8*)(rel_bf + (size_t)(wu >> 16)     * DD + gl * 8);
        }
#pragma unroll
        for (int u = 0; u < 8; ++u) w[u] = bucket[voff(vbase + 8 + u)]; // prefetch
#pragma unroll
        for (int u = 0; u < 8; ++u)
#pragma unroll
            for (int j = 0; j < 8; ++j)
                acc[j] += (float)a[u][j] + (float)r[u][j];
    }

    bf16x8 o;
#pragma unroll
    for (int j = 0; j < 8; ++j) o[j] = (__bf16)(acc[j] * sc);
    *(bf16x8*)&As[g * AP + gl * 8] = o;
    *(bf16x8*)&As[g * AP + DD + gl * 8] = own_h;
    __syncthreads();

    // ---- phase 2: MFMA. wave w -> n-tiles 2w, 2w+1 over shared 16 A-rows.
    int lane = tid & 63;
    int wave = tid >> 6;
    int aoff = (lane & 15) * AP + (lane >> 4) * 8;

    f32x4 c0 = (f32x4)0.f, c1 = (f32x4)0.f;
    int nt0 = wave * 2;
#pragma unroll
    for (int kstep = 0; kstep < 8; ++kstep) {
        bf16x8 a = *(const bf16x8*)&As[aoff + kstep * 32];
        const __bf16* bbase = Bp + ((size_t)(kstep * 8 + nt0) * 64 + lane) * 8;
        bf16x8 b0 = *(const bf16x8*)bbase;
        bf16x8 b1 = *(const bf16x8*)(bbase + 64 * 8);
        c0 = __builtin_amdgcn_mfma_f32_16x16x32_bf16(a, b0, c0, 0, 0, 0);
        c1 = __builtin_amdgcn_mfma_f32_16x16x32_bf16(a, b1, c1, 0, 0, 0);
    }

    // epilogue: C/D layout col=lane&15, row=(lane>>4)*4+reg; rows all < NN.
    // nontemporal: out is a 25.6MB single-use stream; don't evict h_bf from L2
    int quad = lane >> 4;
    int col  = lane & 15;
#pragma unroll
    for (int reg = 0; reg < 4; ++reg) {
        float* op = out + (size_t)(row0 + quad * 4 + reg) * DD + col;
        __builtin_nontemporal_store(fmaxf(c0[reg], 0.f), op + nt0 * 16);
        __builtin_nontemporal_store(fmaxf(c1[reg], 0.f), op + (nt0 + 1) * 16);
    }
}

extern "C" void kernel_launch(void* const* d_in, const int* in_sizes, int n_in,
                              void* d_out, int out_size, void* d_ws, size_t ws_size,
                              hipStream_t stream) {
    const float* h    = (const float*)d_in[0];
    const float* norm = (const float*)d_in[1];
    const float* rel  = (const float*)d_in[2];
    const float* W    = (const float*)d_in[3];
    const float* L    = (const float*)d_in[4];
    const int* esrc   = (const int*)d_in[5];
    const int* edst   = (const int*)d_in[6];
    const int* etyp   = (const int*)d_in[7];
    float* out = (float*)d_out;

    int* ws = (int*)d_ws;
    unsigned* bucket = (unsigned*)(ws + OFF_BKT);
    __bf16* h_bf     = (__bf16*)(ws + OFF_HB);
    __bf16* rel_bf   = (__bf16*)(ws + OFF_RELB);
    __bf16* Bp       = (__bf16*)(ws + OFF_BP);

    prep_fill<<<PREP_BLOCKS, 256, 0, stream>>>(h, rel, W, L, h_bf, rel_bf, Bp,
                                               esrc, edst, etyp, bucket);
    fused_gather_mfma<<<NN / 16, 256, 0, stream>>>(h_bf, rel_bf, norm,
                                                   bucket, Bp, out);
}